// Round 3
// baseline (163.956 us; speedup 1.0000x reference)
//
#include <hip/hip_runtime.h>

// ADDA local attention, K=3, dilation=1, head_dim=64.
// Shapes (fixed by setup_inputs): q,k,v = [B=8, d=512, H=56, W=56] fp32,
// out = [B, H, W, d] fp32. h = d/64 = 8 heads.
//
// Semantics (matches zero-padded unfold reference):
//   logits[n] = SCALE * sum_c q[c] * k_pad[neighbor n, c]   (OOB -> logit 0)
//   w = softmax over ALL 9 logits (zeros included)
//   out[c] = sum_n w[n] * v_pad[neighbor n, c]              (OOB v -> 0)

namespace {

constexpr int HD = 64;          // head_dim
constexpr int HH = 56;
constexpr int WW = 56;
constexpr int HW = HH * WW;     // 3136
constexpr int CS = HW;          // channel stride in elements
constexpr int NHEAD = 8;        // heads per image (d=512)
constexpr int DTOT = 512;       // total channels
constexpr float SCALE = 0.125f; // 64^-0.5
constexpr int PBLK = 256;       // pixels per block
constexpr int NPB = (HW + PBLK - 1) / PBLK;  // 13

__global__ __launch_bounds__(256)
void adda_fwd(const float* __restrict__ q, const float* __restrict__ k,
              const float* __restrict__ v, float* __restrict__ out) {
  const int pb = blockIdx.x % NPB;
  const int bh = blockIdx.x / NPB;              // b*NHEAD + head
  const int p  = pb * PBLK + (int)threadIdx.x;  // pixel index y*56+x
  if (p >= HW) return;

  const int y = p / WW;
  const int x = p - y * WW;

  // q[b, head*64+c, y, x]: channel block for this (b,head) starts at bh*64.
  const int base = bh * (HD * HW) + p;
  const float* __restrict__ qp = q + base;
  const float* __restrict__ kp = k + base;
  const float* __restrict__ vp = v + base;

  // Neighbor offsets; OOB clamped to self (result discarded).
  int  soff[9];
  bool valid[9];
#pragma unroll
  for (int n = 0; n < 9; ++n) {
    const int dy = n / 3 - 1;
    const int dx = n % 3 - 1;
    const bool ok = ((unsigned)(y + dy) < (unsigned)HH) &&
                    ((unsigned)(x + dx) < (unsigned)WW);
    valid[n] = ok;
    soff[n]  = ok ? dy * WW + dx : 0;
  }

  // Pass 1: logits over 64 channels.
  float logits[9];
#pragma unroll
  for (int n = 0; n < 9; ++n) logits[n] = 0.f;

#pragma unroll 4
  for (int c = 0; c < HD; ++c) {
    const float qv = qp[c * CS];
#pragma unroll
    for (int n = 0; n < 9; ++n)
      logits[n] = fmaf(qv, kp[c * CS + soff[n]], logits[n]);
  }

  // Zero-padded unfold: OOB logits are exactly 0 and participate in softmax.
#pragma unroll
  for (int n = 0; n < 9; ++n)
    logits[n] = valid[n] ? logits[n] * SCALE : 0.f;

  float m = logits[0];
#pragma unroll
  for (int n = 1; n < 9; ++n) m = fmaxf(m, logits[n]);

  float w[9];
  float denom = 0.f;
#pragma unroll
  for (int n = 0; n < 9; ++n) {
    w[n] = __expf(logits[n] - m);
    denom += w[n];
  }
  const float inv = 1.f / denom;
#pragma unroll
  for (int n = 0; n < 9; ++n)
    w[n] = valid[n] ? w[n] * inv : 0.f;  // OOB v is zero -> drop its weight

  // Pass 2: weighted sum of v, write channels-last.
  const int b    = bh >> 3;       // NHEAD == 8
  const int head = bh & 7;
  float* __restrict__ op = out + ((long)b * HW + p) * DTOT + head * HD;

#pragma unroll 4
  for (int c = 0; c < HD; ++c) {
    float acc = 0.f;
#pragma unroll
    for (int n = 0; n < 9; ++n)
      acc = fmaf(w[n], vp[c * CS + soff[n]], acc);
    op[c] = acc;
  }
}

} // namespace

extern "C" void kernel_launch(void* const* d_in, const int* in_sizes, int n_in,
                              void* d_out, int out_size, void* d_ws, size_t ws_size,
                              hipStream_t stream) {
  const float* q = (const float*)d_in[0];
  const float* k = (const float*)d_in[1];
  const float* v = (const float*)d_in[2];
  float* out = (float*)d_out;

  const int BH = in_sizes[0] / (HD * HW);  // B * NHEAD = 64
  dim3 grid(BH * NPB);
  adda_fwd<<<grid, 256, 0, stream>>>(q, k, v, out);
}

// Round 4
// 79.831 us; speedup vs baseline: 2.0538x; 2.0538x over previous
//
#include <hip/hip_runtime.h>

// ADDA local attention, K=3, dilation=1, head_dim=64.
// q,k,v = [B=8, d=512, H=56, W=56] fp32 (channel-major), out = [B,H,W,d] fp32.
// h = 8 heads of 64 channels.
//
// Round-3 counters: latency-bound (Occupancy 33%, VALUBusy 5.8%, HBM 10%).
// This version splits channels across 4 thread-groups per pixel:
//   tid = cg*64 + px ; each thread does 16 channels of the logit pass,
//   partial logits reduced via LDS, softmax recomputed per thread,
//   then 16 channels of the V pass with float4 stores.
// 4x more waves (49/CU vs 13/CU), 4x fewer VMEM instrs per thread.

namespace {

constexpr int HD = 64;          // head_dim
constexpr int HH = 56;
constexpr int WW = 56;
constexpr int HW = HH * WW;     // 3136
constexpr int CS = HW;          // channel stride (elements)
constexpr int DTOT = 512;
constexpr float SCALE = 0.125f; // 64^-0.5
constexpr int PXB = 64;         // pixels per block
constexpr int NPB = HW / PXB;   // 49 (exact)
constexpr int CPG = 16;         // channels per thread-group
constexpr int NCG = 4;          // channel groups (NCG*CPG = HD)

__global__ __launch_bounds__(256)
void adda_fwd(const float* __restrict__ q, const float* __restrict__ k,
              const float* __restrict__ v, float* __restrict__ out) {
  const int pb = blockIdx.x % NPB;
  const int bh = blockIdx.x / NPB;       // b*8 + head
  const int px = (int)threadIdx.x & 63;  // pixel lane within block
  const int cg = (int)threadIdx.x >> 6;  // channel group 0..3
  const int p  = pb * PXB + px;          // pixel index y*56+x

  const int y = p / WW;
  const int x = p - y * WW;

  // this thread's 16-channel slab for (b,head)
  const int base = bh * (HD * HW) + cg * (CPG * HW) + p;
  const float* __restrict__ qp = q + base;
  const float* __restrict__ kp = k + base;
  const float* __restrict__ vp = v + base;

  int  soff[9];
  bool valid[9];
#pragma unroll
  for (int n = 0; n < 9; ++n) {
    const int dy = n / 3 - 1;
    const int dx = n % 3 - 1;
    const bool ok = ((unsigned)(y + dy) < (unsigned)HH) &&
                    ((unsigned)(x + dx) < (unsigned)WW);
    valid[n] = ok;
    soff[n]  = ok ? dy * WW + dx : 0;
  }

  // ---- Pass 1: partial logits over this thread's 16 channels ----
  float lg[9];
#pragma unroll
  for (int n = 0; n < 9; ++n) lg[n] = 0.f;

#pragma unroll 4
  for (int c = 0; c < CPG; ++c) {
    const float qv = qp[c * CS];
#pragma unroll
    for (int n = 0; n < 9; ++n)
      lg[n] = fmaf(qv, kp[c * CS + soff[n]], lg[n]);
  }

  // ---- reduce partials across the 4 channel groups via LDS ----
  // lane stride = 9 dwords, gcd(9,32)=1 -> conflict-free
  __shared__ float part[NCG][PXB][9];
#pragma unroll
  for (int n = 0; n < 9; ++n) part[cg][px][n] = lg[n];
  __syncthreads();

  float logits[9];
#pragma unroll
  for (int n = 0; n < 9; ++n) {
    logits[n] = (part[0][px][n] + part[1][px][n]) +
                (part[2][px][n] + part[3][px][n]);
  }

  // zero-padded unfold: OOB logits are exactly 0 and join the softmax
#pragma unroll
  for (int n = 0; n < 9; ++n)
    logits[n] = valid[n] ? logits[n] * SCALE : 0.f;

  float m = logits[0];
#pragma unroll
  for (int n = 1; n < 9; ++n) m = fmaxf(m, logits[n]);

  float w[9];
  float denom = 0.f;
#pragma unroll
  for (int n = 0; n < 9; ++n) {
    w[n] = __expf(logits[n] - m);
    denom += w[n];
  }
  const float inv = 1.f / denom;
#pragma unroll
  for (int n = 0; n < 9; ++n)
    w[n] = valid[n] ? w[n] * inv : 0.f;  // OOB v is zero -> drop weight

  // ---- Pass 2: weighted V over this thread's 16 channels ----
  float4 o[CPG / 4];
#pragma unroll
  for (int cc = 0; cc < CPG / 4; ++cc) {
#pragma unroll
    for (int j = 0; j < 4; ++j) {
      const int c = cc * 4 + j;
      float acc = 0.f;
#pragma unroll
      for (int n = 0; n < 9; ++n)
        acc = fmaf(w[n], vp[c * CS + soff[n]], acc);
      (&o[cc].x)[j] = acc;
    }
  }

  const int b    = bh >> 3;
  const int head = bh & 7;
  float4* __restrict__ op = (float4*)(out +
      ((long)b * HW + p) * DTOT + head * HD + cg * CPG);
#pragma unroll
  for (int cc = 0; cc < CPG / 4; ++cc) op[cc] = o[cc];
}

} // namespace

extern "C" void kernel_launch(void* const* d_in, const int* in_sizes, int n_in,
                              void* d_out, int out_size, void* d_ws, size_t ws_size,
                              hipStream_t stream) {
  const float* q = (const float*)d_in[0];
  const float* k = (const float*)d_in[1];
  const float* v = (const float*)d_in[2];
  float* out = (float*)d_out;

  const int BH = in_sizes[0] / (HD * HW);  // B * 8 heads = 64
  dim3 grid(BH * NPB);
  adda_fwd<<<grid, 256, 0, stream>>>(q, k, v, out);
}